// Round 1
// baseline (12241.496 us; speedup 1.0000x reference)
//
#include <hip/hip_runtime.h>
#include <cstdio>
#include <math.h>

// Problem constants
#define BB 64
#define SS 512
#define HH 256
#define G4 1024   // 4*H
#define TT (BB*SS)  // 32768

__device__ __forceinline__ float sigf(float x){ return 1.0f/(1.0f+expf(-x)); }

// -------------------- prep: combined LSTM bias + zero barrier counters -----
__global__ void prep_kernel(const float* __restrict__ b_ih, const float* __restrict__ b_hh,
                            float* __restrict__ bcomb, unsigned int* __restrict__ cnt){
    int i = blockIdx.x*blockDim.x + threadIdx.x;
    if (i < G4) bcomb[i] = b_ih[i] + b_hh[i];
    if (i < 8)  cnt[i] = 0u;
}

// -------------------- generic fp32 GEMM: C[M,N] = A[M,K] * B[N,K]^T + bias -
// M = 32768 (T rows), K = 256 fixed. 64x64 tile, 256 threads, 4x4 micro-tile.
// Skips 64-row tiles that are entirely past the sequence length.
__global__ __launch_bounds__(256) void gemm_nt(
    const float* __restrict__ A, const float* __restrict__ Bw,
    const float* __restrict__ bias, float* __restrict__ C,
    int N, const int* __restrict__ lengths)
{
    const int K = 256;
    int m0 = blockIdx.y * 64, n0 = blockIdx.x * 64;
    if (lengths){ int b = m0 >> 9, t0 = m0 & 511; if (t0 >= lengths[b]) return; }
    __shared__ float As[16][64];
    __shared__ float Bs[16][64];
    int tid = threadIdx.x;
    int tx = tid & 15, ty = tid >> 4;
    int lr = tid >> 2, lk = (tid & 3) << 2;
    float acc[4][4] = {};
    const float* Aptr = A + (size_t)(m0 + lr)*K + lk;
    const float* Bptr = Bw + (size_t)(n0 + lr)*K + lk;
    for (int k0 = 0; k0 < K; k0 += 16) {
        float4 av = *(const float4*)(Aptr + k0);
        float4 bv = *(const float4*)(Bptr + k0);
        __syncthreads();
        As[lk+0][lr]=av.x; As[lk+1][lr]=av.y; As[lk+2][lr]=av.z; As[lk+3][lr]=av.w;
        Bs[lk+0][lr]=bv.x; Bs[lk+1][lr]=bv.y; Bs[lk+2][lr]=bv.z; Bs[lk+3][lr]=bv.w;
        __syncthreads();
        #pragma unroll
        for (int kk = 0; kk < 16; ++kk) {
            float4 a4 = *(const float4*)&As[kk][ty<<2];
            float4 b4 = *(const float4*)&Bs[kk][tx<<2];
            float av_[4] = {a4.x, a4.y, a4.z, a4.w};
            float bv_[4] = {b4.x, b4.y, b4.z, b4.w};
            #pragma unroll
            for (int i=0;i<4;i++)
                #pragma unroll
                for (int j=0;j<4;j++)
                    acc[i][j] = fmaf(av_[i], bv_[j], acc[i][j]);
        }
    }
    int col = n0 + (tx<<2);
    float4 bb4 = bias ? *(const float4*)&bias[col] : make_float4(0.f,0.f,0.f,0.f);
    #pragma unroll
    for (int i=0;i<4;i++){
        int row = m0 + (ty<<2) + i;
        float4 o;
        o.x = acc[i][0]+bb4.x; o.y = acc[i][1]+bb4.y; o.z = acc[i][2]+bb4.z; o.w = acc[i][3]+bb4.w;
        *(float4*)&C[(size_t)row*N + col] = o;
    }
}

// -------------------- per-row LayerNorm (optional residual add, optional ReLU)
__global__ __launch_bounds__(256) void ln_act(
    float* __restrict__ X, const float* __restrict__ add,
    const float* __restrict__ gg, const float* __restrict__ bb,
    const int* __restrict__ lengths, int relu)
{
    int row = blockIdx.x;
    { int b = row >> 9, t = row & 511; if (t >= lengths[b]) return; }
    int tid = threadIdx.x;
    __shared__ float red[8];
    size_t idx = (size_t)row*HH + tid;
    float v = X[idx];
    if (add) v += add[idx];
    float s = v, q = v*v;
    #pragma unroll
    for (int m=32;m>=1;m>>=1){ s += __shfl_xor(s,m); q += __shfl_xor(q,m); }
    if ((tid&63)==0){ red[tid>>6]=s; red[4+(tid>>6)]=q; }
    __syncthreads();
    s = red[0]+red[1]+red[2]+red[3]; q = red[4]+red[5]+red[6]+red[7];
    float mean = s*(1.f/HH);
    float var  = q*(1.f/HH) - mean*mean;
    float rstd = rsqrtf(var + 1e-5f);
    float o = (v-mean)*rstd*gg[tid] + bb[tid];
    if (relu) o = fmaxf(o, 0.f);
    X[idx] = o;
}

// -------------------- LSTM recurrence ------------------------------------
// 64 blocks = 8 batch-groups (g = bid&7) x 8 hidden-partitions (p = bid>>3).
// Block (g,p): owns batch rows g*8..g*8+7 and hidden dims p*32..p*32+32 (all
// 4 gates -> 128 rows of w_hh, kept in LDS for all steps). Per step: compute
// z-slice from shared h (LDS), update own h/c slice, publish h slice to
// global double-buffer, barrier the 8 p-blocks of the group via device-scope
// atomic counter, reload full h.
__global__ __launch_bounds__(512) void lstm_kernel(
    const float* __restrict__ Zx, const float* __restrict__ whh,
    const int* __restrict__ lengths, float* __restrict__ hglob,
    unsigned int* __restrict__ cnt, float* __restrict__ out)
{
    int bid = blockIdx.x;
    int g = bid & 7, p = bid >> 3;
    int tid = threadIdx.x;
    __shared__ float Wl[128*257];       // 128 rows x 256 k, padded stride 257
    __shared__ float hs[8][256];        // full h for the 8 rows of this group
    __shared__ float zred[4][8][128];   // k-split partial z

    // load w_hh slice: local j = q*32+dd  <->  global row q*256 + p*32 + dd
    {
        int jl = tid >> 2, kq = tid & 3;
        int q = jl >> 5, dd = jl & 31;
        const float* srcw = whh + (size_t)(q*256 + p*32 + dd)*256 + kq*64;
        float* dst = &Wl[jl*257 + kq*64];
        #pragma unroll
        for (int c=0;c<16;c++){
            float4 w4 = *(const float4*)(srcw + c*4);
            dst[c*4+0]=w4.x; dst[c*4+1]=w4.y; dst[c*4+2]=w4.z; dst[c*4+3]=w4.w;
        }
    }
    int Tg = 0;
    #pragma unroll
    for (int r=0;r<8;r++) Tg = max(Tg, lengths[g*8+r]);

    int wv = tid >> 6, lane = tid & 63;
    int jh = wv & 1, kq2 = wv >> 1;
    int j = jh*64 + lane;               // 0..127 local z column
    int gr = tid >> 5, gd = tid & 31;   // gate-thread mapping (tid<256)
    float creg = 0.f;

    __syncthreads();
    for (int i = tid; i < 8*256; i += 512) ((float*)hs)[i] = 0.f;
    __syncthreads();

    for (int s = 0; s < Tg; ++s) {
        // z partial: acc[r] = sum_{k in quarter} hs[r][k] * Wl[j][k]
        float acc[8] = {0.f,0.f,0.f,0.f,0.f,0.f,0.f,0.f};
        const float* wrow = &Wl[j*257 + kq2*64];
        #pragma unroll
        for (int c=0;c<16;c++){
            int kb = kq2*64 + c*4;
            float w0 = wrow[c*4+0], w1 = wrow[c*4+1], w2 = wrow[c*4+2], w3 = wrow[c*4+3];
            #pragma unroll
            for (int r=0;r<8;r++){
                float4 h4 = *(const float4*)&hs[r][kb];
                acc[r] = fmaf(h4.x,w0, fmaf(h4.y,w1, fmaf(h4.z,w2, fmaf(h4.w,w3, acc[r]))));
            }
        }
        #pragma unroll
        for (int r=0;r<8;r++) zred[kq2][r][j] = acc[r];
        __syncthreads();

        if (tid < 256) {
            int row = g*8 + gr;
            float z[4];
            #pragma unroll
            for (int q2=0;q2<4;q2++){
                int jl = q2*32 + gd;
                float zz = zred[0][gr][jl]+zred[1][gr][jl]+zred[2][gr][jl]+zred[3][gr][jl];
                zz += Zx[((size_t)row*SS + s)*G4 + (q2*256 + p*32 + gd)];
                z[q2] = zz;
            }
            creg = sigf(z[1])*creg + sigf(z[0])*tanhf(z[2]);
            float hvv = sigf(z[3])*tanhf(creg);
            hglob[(size_t)((s+1)&1)*(64*256) + (size_t)row*256 + p*32 + gd] = hvv;
            out[((size_t)row*SS + s)*HH + p*32 + gd] = hvv;
        }
        __threadfence();
        __syncthreads();
        if (tid == 0) {
            __hip_atomic_fetch_add(&cnt[g], 1u, __ATOMIC_ACQ_REL, __HIP_MEMORY_SCOPE_AGENT);
            unsigned tgt = (unsigned)(s+1)*8u;
            while (__hip_atomic_load(&cnt[g], __ATOMIC_ACQUIRE, __HIP_MEMORY_SCOPE_AGENT) < tgt) { }
        }
        __syncthreads();
        __threadfence();
        {   // reload full h for the group from the just-written buffer
            const float* hsrc = hglob + (size_t)((s+1)&1)*(64*256) + (size_t)g*8*256;
            for (int i = tid; i < 2048; i += 512) ((float*)hs)[i] = hsrc[i];
        }
        __syncthreads();
    }
}

// -------------------- attention: one block per (b, head), flash-style ----
__global__ __launch_bounds__(256) void attn_kernel(
    const float* __restrict__ qkv, const int* __restrict__ lengths, float* __restrict__ ctx)
{
    int bh = blockIdx.x; int b = bh >> 3, h = bh & 7;
    int len = lengths[b];
    int tid = threadIdx.x;
    __shared__ float Ks[512][32];
    __shared__ float Vs[512][32];
    for (int i = tid; i < len*32; i += 256){
        int s = i >> 5, d = i & 31;
        size_t base = ((size_t)b*512 + s)*768 + h*32 + d;
        Ks[s][d] = qkv[base + 256];
        Vs[s][d] = qkv[base + 512];
    }
    __syncthreads();
    const float rs = 0.1767766952966369f;   // 1/sqrt(32)
    for (int q0 = 0; q0 < 512; q0 += 256){
        int q = q0 + tid;
        if (q >= len) continue;
        float qr[32];
        size_t qb = ((size_t)b*512 + q)*768 + h*32;
        #pragma unroll
        for (int d=0; d<32; d+=4){
            float4 t4 = *(const float4*)&qkv[qb+d];
            qr[d]=t4.x; qr[d+1]=t4.y; qr[d+2]=t4.z; qr[d+3]=t4.w;
        }
        float m = -3.4e38f, l = 0.f, acc[32];
        #pragma unroll
        for (int d=0;d<32;d++) acc[d]=0.f;
        for (int k=0;k<len;k++){
            float sc = 0.f;
            #pragma unroll
            for (int d=0;d<32;d+=4){
                float4 kv = *(const float4*)&Ks[k][d];
                sc += qr[d]*kv.x + qr[d+1]*kv.y + qr[d+2]*kv.z + qr[d+3]*kv.w;
            }
            sc *= rs;
            float nm = fmaxf(m, sc);
            float f  = expf(m - nm);
            float pc = expf(sc - nm);
            l = l*f + pc;
            #pragma unroll
            for (int d=0;d<32;d+=4){
                float4 vv = *(const float4*)&Vs[k][d];
                acc[d]   = acc[d]*f   + pc*vv.x;
                acc[d+1] = acc[d+1]*f + pc*vv.y;
                acc[d+2] = acc[d+2]*f + pc*vv.z;
                acc[d+3] = acc[d+3]*f + pc*vv.w;
            }
            m = nm;
        }
        float inv = 1.f/l;
        size_t cb = ((size_t)b*512 + q)*256 + h*32;
        #pragma unroll
        for (int d=0;d<32;d+=4){
            float4 o; o.x=acc[d]*inv; o.y=acc[d+1]*inv; o.z=acc[d+2]*inv; o.w=acc[d+3]*inv;
            *(float4*)&ctx[cb+d] = o;
        }
    }
}

// -------------------- Switch MoE (top-1) + LN2, one block per valid token -
__global__ __launch_bounds__(256) void moe_kernel(
    const float* __restrict__ src, const float* __restrict__ rw,
    const float* __restrict__ w1, const float* __restrict__ b1,
    const float* __restrict__ w2, const float* __restrict__ b2,
    const float* __restrict__ g2, const float* __restrict__ bt2,
    const int* __restrict__ lengths, float* __restrict__ out)
{
    int row = blockIdx.x;
    { int bb = row >> 9, t = row & 511; if (t >= lengths[bb]) return; }
    int tid = threadIdx.x;
    __shared__ float sv[256];
    __shared__ float hv[256];
    __shared__ float red[8];
    __shared__ float lsh[8];
    __shared__ int eidx;
    float x = src[(size_t)row*256 + tid];
    sv[tid] = x;
    __syncthreads();
    // router logits (src @ router_w[256,5])
    for (int e=0; e<5; ++e){
        float v = x * rw[tid*5 + e];
        #pragma unroll
        for (int m=32;m>=1;m>>=1) v += __shfl_xor(v,m);
        if ((tid&63)==0) red[tid>>6] = v;
        __syncthreads();
        if (tid==0) lsh[e] = red[0]+red[1]+red[2]+red[3];
        __syncthreads();
    }
    if (tid==0){
        float mx = lsh[0]; int ix = 0;
        for (int e=1;e<5;e++) if (lsh[e] > mx){ mx = lsh[e]; ix = e; }
        float ssum = 0.f;
        for (int e=0;e<5;e++) ssum += expf(lsh[e]-mx);
        lsh[5] = 1.0f/ssum;     // gate = max prob
        eidx = ix;
    }
    __syncthreads();
    int e = eidx; float gate = lsh[5];
    const float* W1 = w1 + (size_t)e*65536;
    float acc = b1[e*256 + tid];
    for (int d=0; d<256; ++d) acc = fmaf(sv[d], W1[(size_t)d*256 + tid], acc);
    hv[tid] = fmaxf(acc, 0.f);
    __syncthreads();
    const float* W2 = w2 + (size_t)e*65536;
    float acc2 = b2[e*256 + tid];
    for (int d=0; d<256; ++d) acc2 = fmaf(hv[d], W2[(size_t)d*256 + tid], acc2);
    float r = x + gate*acc2;
    float s = r, q = r*r;
    #pragma unroll
    for (int m=32;m>=1;m>>=1){ s += __shfl_xor(s,m); q += __shfl_xor(q,m); }
    __syncthreads();
    if ((tid&63)==0){ red[tid>>6]=s; red[4+(tid>>6)]=q; }
    __syncthreads();
    s = red[0]+red[1]+red[2]+red[3]; q = red[4]+red[5]+red[6]+red[7];
    float mean = s*(1.f/256.f), var = q*(1.f/256.f)-mean*mean, rstd = rsqrtf(var+1e-5f);
    out[(size_t)row*256 + tid] = (r-mean)*rstd*g2[tid] + bt2[tid];
}

// -------------------- masked mean pool ------------------------------------
__global__ __launch_bounds__(256) void pool_kernel(
    const float* __restrict__ out2, const int* __restrict__ lengths, float* __restrict__ pooled)
{
    int b = blockIdx.x, d = threadIdx.x;
    int len = lengths[b];
    float s = 0.f;
    for (int t=0;t<len;t++) s += out2[((size_t)b*512 + t)*256 + d];
    pooled[b*256 + d] = s / (float)len;
}

// -------------------- classifier head -------------------------------------
__global__ __launch_bounds__(256) void cls_kernel(
    const float* __restrict__ pooled, const float* __restrict__ w1,
    const float* __restrict__ b1, const float* __restrict__ lg, const float* __restrict__ lb,
    const float* __restrict__ w2, const float* __restrict__ b2, float* __restrict__ outp)
{
    int b = blockIdx.x, j = threadIdx.x;
    __shared__ float pv[256];
    __shared__ float red[8];
    pv[j] = pooled[b*256 + j];
    __syncthreads();
    float acc = b1[j];
    for (int d=0; d<256; d+=4){
        float4 p4 = *(const float4*)&pv[d];
        const float* wr = &w1[(size_t)j*256 + d];
        acc += p4.x*wr[0] + p4.y*wr[1] + p4.z*wr[2] + p4.w*wr[3];
    }
    float s = acc, q = acc*acc;
    #pragma unroll
    for (int m=32;m>=1;m>>=1){ s += __shfl_xor(s,m); q += __shfl_xor(q,m); }
    int wid = j>>6;
    if ((j&63)==0){ red[wid]=s; red[4+wid]=q; }
    __syncthreads();
    s = red[0]+red[1]+red[2]+red[3]; q = red[4]+red[5]+red[6]+red[7];
    float mean = s*(1.f/256.f), var = q*(1.f/256.f)-mean*mean, rstd = rsqrtf(var+1e-5f);
    float h1v = fmaxf((acc-mean)*rstd*lg[j]+lb[j], 0.f);
    float pr = h1v * w2[j];
    __syncthreads();
    #pragma unroll
    for (int m=32;m>=1;m>>=1) pr += __shfl_xor(pr,m);
    if ((j&63)==0) red[wid] = pr;
    __syncthreads();
    if (j==0) outp[b] = red[0]+red[1]+red[2]+red[3] + b2[0];
}

// ==========================================================================
extern "C" void kernel_launch(void* const* d_in, const int* in_sizes, int n_in,
                              void* d_out, int out_size, void* d_ws, size_t ws_size,
                              hipStream_t stream)
{
    const float* x       = (const float*)d_in[0];
    const int*   lengths = (const int*)  d_in[1];
    const float* fe_w    = (const float*)d_in[2];
    const float* fe_b    = (const float*)d_in[3];
    const float* fe_ln_g = (const float*)d_in[4];
    const float* fe_ln_b = (const float*)d_in[5];
    const float* w_ih    = (const float*)d_in[6];
    const float* w_hh    = (const float*)d_in[7];
    const float* b_ih    = (const float*)d_in[8];
    const float* b_hh    = (const float*)d_in[9];
    const float* attn_w  = (const float*)d_in[10];
    const float* attn_b  = (const float*)d_in[11];
    const float* attn_ow = (const float*)d_in[12];
    const float* attn_ob = (const float*)d_in[13];
    const float* ln1_g   = (const float*)d_in[14];
    const float* ln1_b   = (const float*)d_in[15];
    const float* router_w= (const float*)d_in[16];
    const float* e_w1    = (const float*)d_in[17];
    const float* e_b1    = (const float*)d_in[18];
    const float* e_w2    = (const float*)d_in[19];
    const float* e_b2    = (const float*)d_in[20];
    const float* ln2_g   = (const float*)d_in[21];
    const float* ln2_b   = (const float*)d_in[22];
    const float* cl_w1   = (const float*)d_in[23];
    const float* cl_b1   = (const float*)d_in[24];
    const float* cl_ln_g = (const float*)d_in[25];
    const float* cl_ln_b = (const float*)d_in[26];
    const float* cl_w2   = (const float*)d_in[27];
    const float* cl_b2   = (const float*)d_in[28];
    float* outp = (float*)d_out;

    // workspace layout (floats)
    const size_t NEED = (size_t)50381832 * 4;
    if (ws_size < NEED){
        fprintf(stderr, "kernel_launch: ws too small (%zu < %zu)\n", ws_size, NEED);
        return;
    }
    float* W     = (float*)d_ws;
    float* h0    = W;                    // [T,256]   32MB
    float* Zx    = W + 8388608;          // [T,1024] 128MB
    float* lstm  = W + 41943040;         // [T,256]   32MB
    float* hglob = W + 50331648;         // [2,64,256]
    float* pooled= W + 50364416;         // [64,256]
    float* bcomb = W + 50380800;         // [1024]
    unsigned int* cnt = (unsigned int*)(W + 50381824); // [8]
    // aliases into dead regions
    float* qkv  = Zx;                    // [T,768] (after LSTM consumes Zx)
    float* ctx  = Zx + 25165824;         // [T,256]
    float* aop  = h0;                    // [T,256] (h0 dead after Zx GEMM)
    float* src  = lstm;                  // LN1 in-place
    float* out2 = Zx;                    // [T,256] (qkv/ctx dead)

    prep_kernel<<<dim3(4), 256, 0, stream>>>(b_ih, b_hh, bcomb, cnt);
    // feature extractor GEMM + LN + ReLU
    gemm_nt<<<dim3(4,512), 256, 0, stream>>>(x, fe_w, fe_b, h0, 256, lengths);
    ln_act<<<dim3(32768), 256, 0, stream>>>(h0, nullptr, fe_ln_g, fe_ln_b, lengths, 1);
    // LSTM input projection for all timesteps
    gemm_nt<<<dim3(16,512), 256, 0, stream>>>(h0, w_ih, bcomb, Zx, 1024, lengths);
    // recurrent LSTM
    lstm_kernel<<<dim3(64), 512, 0, stream>>>(Zx, w_hh, lengths, hglob, cnt, lstm);
    // attention
    gemm_nt<<<dim3(12,512), 256, 0, stream>>>(lstm, attn_w, attn_b, qkv, 768, lengths);
    attn_kernel<<<dim3(512), 256, 0, stream>>>(qkv, lengths, ctx);
    gemm_nt<<<dim3(4,512), 256, 0, stream>>>(ctx, attn_ow, attn_ob, aop, 256, lengths);
    // post-norm residual LN1 (in-place into lstm -> src)
    ln_act<<<dim3(32768), 256, 0, stream>>>(src, aop, ln1_g, ln1_b, lengths, 0);
    // MoE + LN2
    moe_kernel<<<dim3(32768), 256, 0, stream>>>(src, router_w, e_w1, e_b1, e_w2, e_b2,
                                                ln2_g, ln2_b, lengths, out2);
    // masked mean pool + classifier
    pool_kernel<<<dim3(64), 256, 0, stream>>>(out2, lengths, pooled);
    cls_kernel<<<dim3(64), 256, 0, stream>>>(pooled, cl_w1, cl_b1, cl_ln_g, cl_ln_b,
                                             cl_w2, cl_b2, outp);
}

// Round 2
// 3497.636 us; speedup vs baseline: 3.4999x; 3.4999x over previous
//
#include <hip/hip_runtime.h>
#include <cstdio>
#include <math.h>

// Problem constants
#define BB 64
#define SS 512
#define HH 256
#define G4 1024   // 4*H
#define TT (BB*SS)  // 32768

__device__ __forceinline__ float sigf(float x){ return 1.0f/(1.0f+expf(-x)); }

// -------------------- prep: combined LSTM bias + zero barrier counters -----
__global__ void prep_kernel(const float* __restrict__ b_ih, const float* __restrict__ b_hh,
                            float* __restrict__ bcomb, unsigned int* __restrict__ cnt){
    int i = blockIdx.x*blockDim.x + threadIdx.x;
    if (i < G4) bcomb[i] = b_ih[i] + b_hh[i];
    if (i < 8)  cnt[i] = 0u;
}

// -------------------- generic fp32 GEMM: C[M,N] = A[M,K] * B[N,K]^T + bias -
// M = 32768 (T rows), K = 256 fixed. 64x64 tile, 256 threads, 4x4 micro-tile.
// Skips 64-row tiles that are entirely past the sequence length.
__global__ __launch_bounds__(256) void gemm_nt(
    const float* __restrict__ A, const float* __restrict__ Bw,
    const float* __restrict__ bias, float* __restrict__ C,
    int N, const int* __restrict__ lengths)
{
    const int K = 256;
    int m0 = blockIdx.y * 64, n0 = blockIdx.x * 64;
    if (lengths){ int b = m0 >> 9, t0 = m0 & 511; if (t0 >= lengths[b]) return; }
    __shared__ float As[16][64];
    __shared__ float Bs[16][64];
    int tid = threadIdx.x;
    int tx = tid & 15, ty = tid >> 4;
    int lr = tid >> 2, lk = (tid & 3) << 2;
    float acc[4][4] = {};
    const float* Aptr = A + (size_t)(m0 + lr)*K + lk;
    const float* Bptr = Bw + (size_t)(n0 + lr)*K + lk;
    for (int k0 = 0; k0 < K; k0 += 16) {
        float4 av = *(const float4*)(Aptr + k0);
        float4 bv = *(const float4*)(Bptr + k0);
        __syncthreads();
        As[lk+0][lr]=av.x; As[lk+1][lr]=av.y; As[lk+2][lr]=av.z; As[lk+3][lr]=av.w;
        Bs[lk+0][lr]=bv.x; Bs[lk+1][lr]=bv.y; Bs[lk+2][lr]=bv.z; Bs[lk+3][lr]=bv.w;
        __syncthreads();
        #pragma unroll
        for (int kk = 0; kk < 16; ++kk) {
            float4 a4 = *(const float4*)&As[kk][ty<<2];
            float4 b4 = *(const float4*)&Bs[kk][tx<<2];
            float av_[4] = {a4.x, a4.y, a4.z, a4.w};
            float bv_[4] = {b4.x, b4.y, b4.z, b4.w};
            #pragma unroll
            for (int i=0;i<4;i++)
                #pragma unroll
                for (int j=0;j<4;j++)
                    acc[i][j] = fmaf(av_[i], bv_[j], acc[i][j]);
        }
    }
    int col = n0 + (tx<<2);
    float4 bb4 = bias ? *(const float4*)&bias[col] : make_float4(0.f,0.f,0.f,0.f);
    #pragma unroll
    for (int i=0;i<4;i++){
        int row = m0 + (ty<<2) + i;
        float4 o;
        o.x = acc[i][0]+bb4.x; o.y = acc[i][1]+bb4.y; o.z = acc[i][2]+bb4.z; o.w = acc[i][3]+bb4.w;
        *(float4*)&C[(size_t)row*N + col] = o;
    }
}

// -------------------- per-row LayerNorm (optional residual add, optional ReLU)
__global__ __launch_bounds__(256) void ln_act(
    float* __restrict__ X, const float* __restrict__ add,
    const float* __restrict__ gg, const float* __restrict__ bb,
    const int* __restrict__ lengths, int relu)
{
    int row = blockIdx.x;
    { int b = row >> 9, t = row & 511; if (t >= lengths[b]) return; }
    int tid = threadIdx.x;
    __shared__ float red[8];
    size_t idx = (size_t)row*HH + tid;
    float v = X[idx];
    if (add) v += add[idx];
    float s = v, q = v*v;
    #pragma unroll
    for (int m=32;m>=1;m>>=1){ s += __shfl_xor(s,m); q += __shfl_xor(q,m); }
    if ((tid&63)==0){ red[tid>>6]=s; red[4+(tid>>6)]=q; }
    __syncthreads();
    s = red[0]+red[1]+red[2]+red[3]; q = red[4]+red[5]+red[6]+red[7];
    float mean = s*(1.f/HH);
    float var  = q*(1.f/HH) - mean*mean;
    float rstd = rsqrtf(var + 1e-5f);
    float o = (v-mean)*rstd*gg[tid] + bb[tid];
    if (relu) o = fmaxf(o, 0.f);
    X[idx] = o;
}

// -------------------- LSTM recurrence ------------------------------------
// 64 blocks = 8 batch-groups (g = bid&7) x 8 hidden-partitions (p = bid>>3).
// Block (g,p): owns batch rows g*8..g*8+7 and hidden dims p*32..p*32+32 (all
// 4 gates -> 128 rows of w_hh, kept in LDS for all steps).
// Cross-block h exchange uses RELAXED agent-scope atomics (global_load/store
// with sc1 -> straight to the device coherence point, NO buffer_wbl2 /
// buffer_inv cache maintenance). __syncthreads() drains vmcnt(0) before
// s_barrier, so published h is globally visible before tid0's fetch_add.
__global__ __launch_bounds__(512) void lstm_kernel(
    const float* __restrict__ Zx, const float* __restrict__ whh,
    const int* __restrict__ lengths, float* __restrict__ hglob,
    unsigned int* __restrict__ cnt, float* __restrict__ out)
{
    int bid = blockIdx.x;
    int g = bid & 7, p = bid >> 3;
    int tid = threadIdx.x;
    __shared__ float Wl[128*257];       // 128 rows x 256 k, padded stride 257
    __shared__ float hs[8][256];        // full h for the 8 rows of this group
    __shared__ float zred[4][8][128];   // k-split partial z

    // load w_hh slice: local j = q*32+dd  <->  global row q*256 + p*32 + dd
    {
        int jl = tid >> 2, kq = tid & 3;
        int q = jl >> 5, dd = jl & 31;
        const float* srcw = whh + (size_t)(q*256 + p*32 + dd)*256 + kq*64;
        float* dst = &Wl[jl*257 + kq*64];
        #pragma unroll
        for (int c=0;c<16;c++){
            float4 w4 = *(const float4*)(srcw + c*4);
            dst[c*4+0]=w4.x; dst[c*4+1]=w4.y; dst[c*4+2]=w4.z; dst[c*4+3]=w4.w;
        }
    }
    int Tg = 0;
    #pragma unroll
    for (int r=0;r<8;r++) Tg = max(Tg, lengths[g*8+r]);

    int wv = tid >> 6, lane = tid & 63;
    int jh = wv & 1, kq2 = wv >> 1;
    int j = jh*64 + lane;               // 0..127 local z column
    int gr = tid >> 5, gd = tid & 31;   // gate-thread mapping (tid<256)
    float creg = 0.f;

    unsigned long long* hgl64 = (unsigned long long*)hglob;

    __syncthreads();
    for (int i = tid; i < 8*256; i += 512) ((float*)hs)[i] = 0.f;
    __syncthreads();

    // prefetch Zx gate slice for step 0
    float zx0=0.f, zx1=0.f, zx2=0.f, zx3=0.f;
    int row = g*8 + gr;
    size_t zbase = (size_t)row*SS*G4 + (size_t)(p*32 + gd);
    if (tid < 256 && Tg > 0){
        zx0 = Zx[zbase +   0];
        zx1 = Zx[zbase + 256];
        zx2 = Zx[zbase + 512];
        zx3 = Zx[zbase + 768];
    }

    for (int s = 0; s < Tg; ++s) {
        // z partial: acc[r] = sum_{k in quarter} hs[r][k] * Wl[j][k]
        float acc[8] = {0.f,0.f,0.f,0.f,0.f,0.f,0.f,0.f};
        const float* wrow = &Wl[j*257 + kq2*64];
        #pragma unroll
        for (int c=0;c<16;c++){
            int kb = kq2*64 + c*4;
            float w0 = wrow[c*4+0], w1 = wrow[c*4+1], w2 = wrow[c*4+2], w3 = wrow[c*4+3];
            #pragma unroll
            for (int r=0;r<8;r++){
                float4 h4 = *(const float4*)&hs[r][kb];
                acc[r] = fmaf(h4.x,w0, fmaf(h4.y,w1, fmaf(h4.z,w2, fmaf(h4.w,w3, acc[r]))));
            }
        }
        #pragma unroll
        for (int r=0;r<8;r++) zred[kq2][r][j] = acc[r];
        __syncthreads();

        int buf = (s+1) & 1;
        if (tid < 256) {
            float z[4];
            #pragma unroll
            for (int q2=0;q2<4;q2++){
                int jl = q2*32 + gd;
                z[q2] = zred[0][gr][jl]+zred[1][gr][jl]+zred[2][gr][jl]+zred[3][gr][jl];
            }
            z[0] += zx0; z[1] += zx1; z[2] += zx2; z[3] += zx3;
            creg = sigf(z[1])*creg + sigf(z[0])*tanhf(z[2]);
            float hvv = sigf(z[3])*tanhf(creg);
            // publish own h slice: write-through to coherence point (sc1)
            __hip_atomic_store(&hglob[(size_t)buf*(64*256) + (size_t)row*256 + p*32 + gd],
                               hvv, __ATOMIC_RELAXED, __HIP_MEMORY_SCOPE_AGENT);
            out[((size_t)row*SS + s)*HH + p*32 + gd] = hvv;
            // prefetch Zx for next step (independent of h exchange)
            if (s+1 < Tg){
                size_t zb = zbase + (size_t)(s+1)*G4;
                zx0 = Zx[zb +   0];
                zx1 = Zx[zb + 256];
                zx2 = Zx[zb + 512];
                zx3 = Zx[zb + 768];
            }
        }
        // __syncthreads drains vmcnt(0): all publishes are at the coherence
        // point before any thread passes.
        __syncthreads();
        if (tid == 0) {
            __hip_atomic_fetch_add(&cnt[g], 1u, __ATOMIC_RELAXED, __HIP_MEMORY_SCOPE_AGENT);
            unsigned tgt = (unsigned)(s+1)*8u;
            while (__hip_atomic_load(&cnt[g], __ATOMIC_RELAXED, __HIP_MEMORY_SCOPE_AGENT) < tgt) { }
        }
        __syncthreads();
        {   // reload full group h from coherence point (sc1 loads, 2x u64/thread)
            size_t base64 = (size_t)buf*8192 + (size_t)g*1024;
            unsigned long long* hd = (unsigned long long*)hs;
            #pragma unroll
            for (int c=0;c<2;c++){
                int i = tid + c*512;
                unsigned long long v = __hip_atomic_load(&hgl64[base64 + i],
                                        __ATOMIC_RELAXED, __HIP_MEMORY_SCOPE_AGENT);
                hd[i] = v;
            }
        }
        __syncthreads();
    }
}

// -------------------- attention: one block per (b, head), flash-style ----
__global__ __launch_bounds__(256) void attn_kernel(
    const float* __restrict__ qkv, const int* __restrict__ lengths, float* __restrict__ ctx)
{
    int bh = blockIdx.x; int b = bh >> 3, h = bh & 7;
    int len = lengths[b];
    int tid = threadIdx.x;
    __shared__ float Ks[512][32];
    __shared__ float Vs[512][32];
    for (int i = tid; i < len*32; i += 256){
        int s = i >> 5, d = i & 31;
        size_t base = ((size_t)b*512 + s)*768 + h*32 + d;
        Ks[s][d] = qkv[base + 256];
        Vs[s][d] = qkv[base + 512];
    }
    __syncthreads();
    const float rs = 0.1767766952966369f;   // 1/sqrt(32)
    for (int q0 = 0; q0 < 512; q0 += 256){
        int q = q0 + tid;
        if (q >= len) continue;
        float qr[32];
        size_t qb = ((size_t)b*512 + q)*768 + h*32;
        #pragma unroll
        for (int d=0; d<32; d+=4){
            float4 t4 = *(const float4*)&qkv[qb+d];
            qr[d]=t4.x; qr[d+1]=t4.y; qr[d+2]=t4.z; qr[d+3]=t4.w;
        }
        float m = -3.4e38f, l = 0.f, acc[32];
        #pragma unroll
        for (int d=0;d<32;d++) acc[d]=0.f;
        for (int k=0;k<len;k++){
            float sc = 0.f;
            #pragma unroll
            for (int d=0;d<32;d+=4){
                float4 kv = *(const float4*)&Ks[k][d];
                sc += qr[d]*kv.x + qr[d+1]*kv.y + qr[d+2]*kv.z + qr[d+3]*kv.w;
            }
            sc *= rs;
            float nm = fmaxf(m, sc);
            float f  = expf(m - nm);
            float pc = expf(sc - nm);
            l = l*f + pc;
            #pragma unroll
            for (int d=0;d<32;d+=4){
                float4 vv = *(const float4*)&Vs[k][d];
                acc[d]   = acc[d]*f   + pc*vv.x;
                acc[d+1] = acc[d+1]*f + pc*vv.y;
                acc[d+2] = acc[d+2]*f + pc*vv.z;
                acc[d+3] = acc[d+3]*f + pc*vv.w;
            }
            m = nm;
        }
        float inv = 1.f/l;
        size_t cb = ((size_t)b*512 + q)*256 + h*32;
        #pragma unroll
        for (int d=0;d<32;d+=4){
            float4 o; o.x=acc[d]*inv; o.y=acc[d+1]*inv; o.z=acc[d+2]*inv; o.w=acc[d+3]*inv;
            *(float4*)&ctx[cb+d] = o;
        }
    }
}

// -------------------- Switch MoE (top-1) + LN2, one block per valid token -
__global__ __launch_bounds__(256) void moe_kernel(
    const float* __restrict__ src, const float* __restrict__ rw,
    const float* __restrict__ w1, const float* __restrict__ b1,
    const float* __restrict__ w2, const float* __restrict__ b2,
    const float* __restrict__ g2, const float* __restrict__ bt2,
    const int* __restrict__ lengths, float* __restrict__ out)
{
    int row = blockIdx.x;
    { int bb = row >> 9, t = row & 511; if (t >= lengths[bb]) return; }
    int tid = threadIdx.x;
    __shared__ float sv[256];
    __shared__ float hv[256];
    __shared__ float red[8];
    __shared__ float lsh[8];
    __shared__ int eidx;
    float x = src[(size_t)row*256 + tid];
    sv[tid] = x;
    __syncthreads();
    // router logits (src @ router_w[256,5])
    for (int e=0; e<5; ++e){
        float v = x * rw[tid*5 + e];
        #pragma unroll
        for (int m=32;m>=1;m>>=1) v += __shfl_xor(v,m);
        if ((tid&63)==0) red[tid>>6] = v;
        __syncthreads();
        if (tid==0) lsh[e] = red[0]+red[1]+red[2]+red[3];
        __syncthreads();
    }
    if (tid==0){
        float mx = lsh[0]; int ix = 0;
        for (int e=1;e<5;e++) if (lsh[e] > mx){ mx = lsh[e]; ix = e; }
        float ssum = 0.f;
        for (int e=0;e<5;e++) ssum += expf(lsh[e]-mx);
        lsh[5] = 1.0f/ssum;     // gate = max prob
        eidx = ix;
    }
    __syncthreads();
    int e = eidx; float gate = lsh[5];
    const float* W1 = w1 + (size_t)e*65536;
    float acc = b1[e*256 + tid];
    for (int d=0; d<256; ++d) acc = fmaf(sv[d], W1[(size_t)d*256 + tid], acc);
    hv[tid] = fmaxf(acc, 0.f);
    __syncthreads();
    const float* W2 = w2 + (size_t)e*65536;
    float acc2 = b2[e*256 + tid];
    for (int d=0; d<256; ++d) acc2 = fmaf(hv[d], W2[(size_t)d*256 + tid], acc2);
    float r = x + gate*acc2;
    float s = r, q = r*r;
    #pragma unroll
    for (int m=32;m>=1;m>>=1){ s += __shfl_xor(s,m); q += __shfl_xor(q,m); }
    __syncthreads();
    if ((tid&63)==0){ red[tid>>6]=s; red[4+(tid>>6)]=q; }
    __syncthreads();
    s = red[0]+red[1]+red[2]+red[3]; q = red[4]+red[5]+red[6]+red[7];
    float mean = s*(1.f/256.f), var = q*(1.f/256.f)-mean*mean, rstd = rsqrtf(var+1e-5f);
    out[(size_t)row*256 + tid] = (r-mean)*rstd*g2[tid] + bt2[tid];
}

// -------------------- masked mean pool ------------------------------------
__global__ __launch_bounds__(256) void pool_kernel(
    const float* __restrict__ out2, const int* __restrict__ lengths, float* __restrict__ pooled)
{
    int b = blockIdx.x, d = threadIdx.x;
    int len = lengths[b];
    float s = 0.f;
    for (int t=0;t<len;t++) s += out2[((size_t)b*512 + t)*256 + d];
    pooled[b*256 + d] = s / (float)len;
}

// -------------------- classifier head -------------------------------------
__global__ __launch_bounds__(256) void cls_kernel(
    const float* __restrict__ pooled, const float* __restrict__ w1,
    const float* __restrict__ b1, const float* __restrict__ lg, const float* __restrict__ lb,
    const float* __restrict__ w2, const float* __restrict__ b2, float* __restrict__ outp)
{
    int b = blockIdx.x, j = threadIdx.x;
    __shared__ float pv[256];
    __shared__ float red[8];
    pv[j] = pooled[b*256 + j];
    __syncthreads();
    float acc = b1[j];
    for (int d=0; d<256; d+=4){
        float4 p4 = *(const float4*)&pv[d];
        const float* wr = &w1[(size_t)j*256 + d];
        acc += p4.x*wr[0] + p4.y*wr[1] + p4.z*wr[2] + p4.w*wr[3];
    }
    float s = acc, q = acc*acc;
    #pragma unroll
    for (int m=32;m>=1;m>>=1){ s += __shfl_xor(s,m); q += __shfl_xor(q,m); }
    int wid = j>>6;
    if ((j&63)==0){ red[wid]=s; red[4+wid]=q; }
    __syncthreads();
    s = red[0]+red[1]+red[2]+red[3]; q = red[4]+red[5]+red[6]+red[7];
    float mean = s*(1.f/256.f), var = q*(1.f/256.f)-mean*mean, rstd = rsqrtf(var+1e-5f);
    float h1v = fmaxf((acc-mean)*rstd*lg[j]+lb[j], 0.f);
    float pr = h1v * w2[j];
    __syncthreads();
    #pragma unroll
    for (int m=32;m>=1;m>>=1) pr += __shfl_xor(pr,m);
    if ((j&63)==0) red[wid] = pr;
    __syncthreads();
    if (j==0) outp[b] = red[0]+red[1]+red[2]+red[3] + b2[0];
}

// ==========================================================================
extern "C" void kernel_launch(void* const* d_in, const int* in_sizes, int n_in,
                              void* d_out, int out_size, void* d_ws, size_t ws_size,
                              hipStream_t stream)
{
    const float* x       = (const float*)d_in[0];
    const int*   lengths = (const int*)  d_in[1];
    const float* fe_w    = (const float*)d_in[2];
    const float* fe_b    = (const float*)d_in[3];
    const float* fe_ln_g = (const float*)d_in[4];
    const float* fe_ln_b = (const float*)d_in[5];
    const float* w_ih    = (const float*)d_in[6];
    const float* w_hh    = (const float*)d_in[7];
    const float* b_ih    = (const float*)d_in[8];
    const float* b_hh    = (const float*)d_in[9];
    const float* attn_w  = (const float*)d_in[10];
    const float* attn_b  = (const float*)d_in[11];
    const float* attn_ow = (const float*)d_in[12];
    const float* attn_ob = (const float*)d_in[13];
    const float* ln1_g   = (const float*)d_in[14];
    const float* ln1_b   = (const float*)d_in[15];
    const float* router_w= (const float*)d_in[16];
    const float* e_w1    = (const float*)d_in[17];
    const float* e_b1    = (const float*)d_in[18];
    const float* e_w2    = (const float*)d_in[19];
    const float* e_b2    = (const float*)d_in[20];
    const float* ln2_g   = (const float*)d_in[21];
    const float* ln2_b   = (const float*)d_in[22];
    const float* cl_w1   = (const float*)d_in[23];
    const float* cl_b1   = (const float*)d_in[24];
    const float* cl_ln_g = (const float*)d_in[25];
    const float* cl_ln_b = (const float*)d_in[26];
    const float* cl_w2   = (const float*)d_in[27];
    const float* cl_b2   = (const float*)d_in[28];
    float* outp = (float*)d_out;

    // workspace layout (floats)
    const size_t NEED = (size_t)50381832 * 4;
    if (ws_size < NEED){
        fprintf(stderr, "kernel_launch: ws too small (%zu < %zu)\n", ws_size, NEED);
        return;
    }
    float* W     = (float*)d_ws;
    float* h0    = W;                    // [T,256]   32MB
    float* Zx    = W + 8388608;          // [T,1024] 128MB
    float* lstm  = W + 41943040;         // [T,256]   32MB
    float* hglob = W + 50331648;         // [2,64,256]
    float* pooled= W + 50364416;         // [64,256]
    float* bcomb = W + 50380800;         // [1024]
    unsigned int* cnt = (unsigned int*)(W + 50381824); // [8]
    // aliases into dead regions
    float* qkv  = Zx;                    // [T,768] (after LSTM consumes Zx)
    float* ctx  = Zx + 25165824;         // [T,256]
    float* aop  = h0;                    // [T,256] (h0 dead after Zx GEMM)
    float* src  = lstm;                  // LN1 in-place
    float* out2 = Zx;                    // [T,256] (qkv/ctx dead)

    prep_kernel<<<dim3(4), 256, 0, stream>>>(b_ih, b_hh, bcomb, cnt);
    // feature extractor GEMM + LN + ReLU
    gemm_nt<<<dim3(4,512), 256, 0, stream>>>(x, fe_w, fe_b, h0, 256, lengths);
    ln_act<<<dim3(32768), 256, 0, stream>>>(h0, nullptr, fe_ln_g, fe_ln_b, lengths, 1);
    // LSTM input projection for all timesteps
    gemm_nt<<<dim3(16,512), 256, 0, stream>>>(h0, w_ih, bcomb, Zx, 1024, lengths);
    // recurrent LSTM
    lstm_kernel<<<dim3(64), 512, 0, stream>>>(Zx, w_hh, lengths, hglob, cnt, lstm);
    // attention
    gemm_nt<<<dim3(12,512), 256, 0, stream>>>(lstm, attn_w, attn_b, qkv, 768, lengths);
    attn_kernel<<<dim3(512), 256, 0, stream>>>(qkv, lengths, ctx);
    gemm_nt<<<dim3(4,512), 256, 0, stream>>>(ctx, attn_ow, attn_ob, aop, 256, lengths);
    // post-norm residual LN1 (in-place into lstm -> src)
    ln_act<<<dim3(32768), 256, 0, stream>>>(src, aop, ln1_g, ln1_b, lengths, 0);
    // MoE + LN2
    moe_kernel<<<dim3(32768), 256, 0, stream>>>(src, router_w, e_w1, e_b1, e_w2, e_b2,
                                                ln2_g, ln2_b, lengths, out2);
    // masked mean pool + classifier
    pool_kernel<<<dim3(64), 256, 0, stream>>>(out2, lengths, pooled);
    cls_kernel<<<dim3(64), 256, 0, stream>>>(pooled, cl_w1, cl_b1, cl_ln_g, cl_ln_b,
                                             cl_w2, cl_b2, outp);
}